// Round 5
// baseline (869.267 us; speedup 1.0000x reference)
//
#include <hip/hip_runtime.h>
#include <hip/hip_bf16.h>

typedef __attribute__((ext_vector_type(8))) short short8;
typedef __attribute__((ext_vector_type(4))) float f32x4;

__device__ __forceinline__ short bf16s(float x) {
    unsigned u = __float_as_uint(x);
    return (short)((u + 0x7fffu + ((u >> 16) & 1u)) >> 16);
}

// ---------------------------------------------------------------------------
// Prep: pack Wm1 (8x64), Wm2 (64x64), Wm3 (64x320) into MFMA B-fragment
// layout (bf16). Frag (t,kh): lane l holds B[k=kh*32+(l>>4)*8+i][col=16t+(l&15)].
// W1B: K=8 only (g==0 lanes nonzero), 4 tiles, kh=0.
// ---------------------------------------------------------------------------
__global__ __launch_bounds__(256) void prep_kernel(
    const float* __restrict__ Wm1, const float* __restrict__ Wm2,
    const float* __restrict__ Wm3,
    short* __restrict__ W1B, short* __restrict__ Wm2B, short* __restrict__ W3B)
{
    int idx = blockIdx.x * 256 + threadIdx.x;   // 52 frags * 64 lanes
    if (idx >= 52 * 64) return;
    int l = idx & 63, f = idx >> 6;
    int g = l >> 4, c = l & 15;
    short8 v;
    if (f < 4) {                 // W1B tile t=f: k=i (g==0), col=16f+c
        #pragma unroll
        for (int i = 0; i < 8; ++i)
            v[i] = (g == 0) ? bf16s(Wm1[(size_t)i * 64 + f * 16 + c]) : (short)0;
        *(short8*)(W1B + (size_t)f * 512 + l * 8) = v;
    } else if (f < 12) {         // Wm2B
        int f2 = f - 4, t = f2 >> 1, kh = f2 & 1;
        #pragma unroll
        for (int i = 0; i < 8; ++i)
            v[i] = bf16s(Wm2[(size_t)(kh * 32 + g * 8 + i) * 64 + t * 16 + c]);
        *(short8*)(Wm2B + (size_t)f2 * 512 + l * 8) = v;
    } else {                     // W3B
        int f3 = f - 12, t = f3 >> 1, kh = f3 & 1;
        #pragma unroll
        for (int i = 0; i < 8; ++i)
            v[i] = bf16s(Wm3[(size_t)(kh * 32 + g * 8 + i) * 320 + t * 16 + c]);
        *(short8*)(W3B + (size_t)f3 * 512 + l * 8) = v;
    }
}

// ---------------------------------------------------------------------------
// CSR build: histogram -> exclusive scan -> bucket fill
// ---------------------------------------------------------------------------
__global__ __launch_bounds__(256) void hist_kernel(
    const int* __restrict__ receivers, int* __restrict__ cnt, int E)
{
    int i = blockIdx.x * 256 + threadIdx.x;
    int stride = gridDim.x * 256;
    for (; i < E; i += stride) atomicAdd(&cnt[receivers[i]], 1);
}

__global__ __launch_bounds__(1024) void scan_kernel(
    const int* __restrict__ cnt, int* __restrict__ offs,
    int* __restrict__ cursor, int N)
{
    __shared__ int a[1024], b[1024];
    int t = threadIdx.x;
    int carry = 0;
    for (int base = 0; base < N; base += 1024) {
        int v = (base + t < N) ? cnt[base + t] : 0;
        a[t] = v;
        __syncthreads();
        int* src = a; int* dst = b;
        for (int off = 1; off < 1024; off <<= 1) {
            dst[t] = src[t] + ((t >= off) ? src[t - off] : 0);
            __syncthreads();
            int* tmp = src; src = dst; dst = tmp;
        }
        int incl = src[t];
        int tot  = src[1023];
        __syncthreads();
        if (base + t < N) {
            int e = carry + incl - v;
            offs[base + t] = e;
            cursor[base + t] = e;
        }
        carry += tot;
    }
    if (t == 0) offs[N] = carry;
}

__global__ __launch_bounds__(256) void fill_kernel(
    const int* __restrict__ receivers, int* __restrict__ cursor,
    int* __restrict__ eidx, int E)
{
    int i = blockIdx.x * 256 + threadIdx.x;
    int stride = gridDim.x * 256;
    for (; i < E; i += stride) {
        int pos = atomicAdd(&cursor[receivers[i]], 1);
        eidx[pos] = i;
    }
}

// ---------------------------------------------------------------------------
// Node up-projection: u[n] = [u0(64) | u1x(64) | u1y(64) | u1z(64)]
// ---------------------------------------------------------------------------
__global__ __launch_bounds__(256) void node_up_kernel(
    const float* __restrict__ node_feats, const float* __restrict__ W0_up,
    const float* __restrict__ W1_up, float* __restrict__ u)
{
    int n = blockIdx.x;
    int t = threadIdx.x;
    const float* nf = node_feats + (size_t)n * 256;
    float f = 0.f;
    if (t < 64) {
        #pragma unroll 8
        for (int c = 0; c < 64; ++c) f += nf[c] * W0_up[c * 64 + t];
        u[(size_t)n * 256 + t] = f;
    } else {
        int i = (t - 64) >> 6;
        int d = t & 63;
        #pragma unroll 8
        for (int c = 0; c < 64; ++c) f += nf[64 + c * 3 + i] * W1_up[c * 64 + d];
        u[(size_t)n * 256 + 64 + i * 64 + d] = f;
    }
}

// ---------------------------------------------------------------------------
// Edge kernel v5: wave per receiver node; 16-edge chunks, ALL 3 MLP layers on
// MFMA. Lanes 0-15 load edge data in one parallel round and build the basis
// A-fragment (K=8 zero-padded to 32). One LDS H-buffer reused for h1 then h2
// (same-wave program order). Derived message terms computed inline per path
// to keep VGPR <= 168 (3 waves/SIMD).
// ---------------------------------------------------------------------------
__global__ __launch_bounds__(256, 3) void edge_kernel(
    const float* __restrict__ vectors, const int* __restrict__ senders,
    const int* __restrict__ eidx, const int* __restrict__ offs,
    const float* __restrict__ u, const short* __restrict__ W1B,
    const short* __restrict__ Wm2B, const short* __restrict__ W3B,
    float* __restrict__ acc, int N)
{
    __shared__ __align__(16) short ldsH[4][1024];     // [wave][16e*64ch] swz
    __shared__ __align__(16) float ldsMeta[4][16][4]; // Y.xyz + sender

    const int lane = threadIdx.x & 63;
    const int wv   = threadIdx.x >> 6;
    const int n    = blockIdx.x * 4 + wv;
    if (n >= N) return;
    const int c = lane & 15, g = lane >> 4;

    float a0q[4]  = {0.f, 0.f, 0.f, 0.f};
    float a1xq[4] = {0.f, 0.f, 0.f, 0.f};
    float a1yq[4] = {0.f, 0.f, 0.f, 0.f};
    float a1zq[4] = {0.f, 0.f, 0.f, 0.f};

    const int beg = offs[n], end = offs[n + 1];

    for (int p0 = beg; p0 < end; p0 += 16) {
        const int m = end - p0;

        // ---- edge prologue: lanes 0-15 own one edge each (parallel loads) --
        short8 basisA = {0, 0, 0, 0, 0, 0, 0, 0};
        if (lane < 16) {
            const bool v = (lane < m);
            const int e = eidx[p0 + (v ? lane : 0)];
            float vx = vectors[3 * (size_t)e + 0];
            float vy = vectors[3 * (size_t)e + 1];
            float vz = vectors[3 * (size_t)e + 2];
            int snd = v ? senders[e] : 0;
            float r = sqrtf(vx * vx + vy * vy + vz * vz);
            float ir = (v && r != 0.f) ? 1.f / r : 0.f;
            *(float4*)&ldsMeta[wv][lane][0] =
                make_float4(vx * ir, vy * ir, vz * ir, __int_as_float(snd));
            // basis[b] = coef * sin((b+1)*pi*r/5) / r, Chebyshev recurrence
            float ang = r * 0.6283185307179586f;
            float s1, c1;
            __sincosf(ang, &s1, &c1);
            float tc = 2.f * c1;
            float sb = s1, sp = 0.f;
            float coef = 0.6324555320336759f * ir;
            #pragma unroll
            for (int b = 0; b < 8; ++b) {
                basisA[b] = bf16s(sb * coef);
                float nx = tc * sb - sp;
                sp = sb; sb = nx;
            }
        }

        // ---- layer 1: 4 MFMAs; silu -> ldsH (swizzled bf16) ----
        #pragma unroll
        for (int t = 0; t < 4; ++t) {
            f32x4 h = {0.f, 0.f, 0.f, 0.f};
            short8 bf = *(const short8*)(W1B + (size_t)t * 512 + lane * 8);
            h = __builtin_amdgcn_mfma_f32_16x16x32_bf16(basisA, bf, h, 0, 0, 0);
            #pragma unroll
            for (int i = 0; i < 4; ++i) {
                float x = h[i];
                float h1 = x / (1.f + __expf(-x));
                int row = 4 * g + i;
                ldsH[wv][row * 64 + ((16 * t + c) ^ ((row & 7) << 3))] = bf16s(h1);
            }
        }
        short8 h1f0 = *(const short8*)&ldsH[wv][c * 64 + ((g * 8) ^ ((c & 7) << 3))];
        short8 h1f1 = *(const short8*)&ldsH[wv][c * 64 + ((32 + g * 8) ^ ((c & 7) << 3))];

        // ---- layer 2: 8 MFMAs; silu -> ldsH (reuse) ----
        #pragma unroll
        for (int t = 0; t < 4; ++t) {
            f32x4 h = {0.f, 0.f, 0.f, 0.f};
            short8 b0 = *(const short8*)(Wm2B + (size_t)(t * 2) * 512 + lane * 8);
            short8 b1 = *(const short8*)(Wm2B + (size_t)(t * 2 + 1) * 512 + lane * 8);
            h = __builtin_amdgcn_mfma_f32_16x16x32_bf16(h1f0, b0, h, 0, 0, 0);
            h = __builtin_amdgcn_mfma_f32_16x16x32_bf16(h1f1, b1, h, 0, 0, 0);
            #pragma unroll
            for (int i = 0; i < 4; ++i) {
                float x = h[i];
                float h2 = x / (1.f + __expf(-x));
                int row = 4 * g + i;
                ldsH[wv][row * 64 + ((16 * t + c) ^ ((row & 7) << 3))] = bf16s(h2);
            }
        }
        short8 h2f0 = *(const short8*)&ldsH[wv][c * 64 + ((g * 8) ^ ((c & 7) << 3))];
        short8 h2f1 = *(const short8*)&ldsH[wv][c * 64 + ((32 + g * 8) ^ ((c & 7) << 3))];

        // ---- per-lane edge meta for its 4 rows ----
        float Yx[4], Yy[4], Yz[4];
        int snd[4];
        #pragma unroll
        for (int i = 0; i < 4; ++i) {
            int row = 4 * g + i;
            float4 mt = *(const float4*)&ldsMeta[wv][row][0];
            Yx[i] = mt.x; Yy[i] = mt.y; Yz[i] = mt.z;
            snd[i] = __float_as_int(mt.w);
        }

        // ---- layer 3 + fused messages (derived terms inline per path) ----
        #pragma unroll
        for (int q = 0; q < 4; ++q) {
            const int d = 16 * q + c;
            float m0[4], m1x[4], m1y[4], m1z[4];
            #pragma unroll
            for (int i = 0; i < 4; ++i) {
                const float* us = u + (size_t)snd[i] * 256 + d;
                m0[i]  = us[0];
                m1x[i] = us[64];
                m1y[i] = us[128];
                m1z[i] = us[192];
            }
            #pragma unroll
            for (int p = 0; p < 5; ++p) {
                const int t = 4 * p + q;
                f32x4 w = {0.f, 0.f, 0.f, 0.f};
                short8 b0 = *(const short8*)(W3B + (size_t)(t * 2) * 512 + lane * 8);
                short8 b1 = *(const short8*)(W3B + (size_t)(t * 2 + 1) * 512 + lane * 8);
                w = __builtin_amdgcn_mfma_f32_16x16x32_bf16(h2f0, b0, w, 0, 0, 0);
                w = __builtin_amdgcn_mfma_f32_16x16x32_bf16(h2f1, b1, w, 0, 0, 0);
                #pragma unroll
                for (int i = 0; i < 4; ++i) {
                    float wv_ = w[i];
                    if (p == 0) {
                        a0q[q] += wv_ * m0[i];
                    } else if (p == 1) {
                        float tt = wv_ * m0[i];
                        a1xq[q] += tt * Yx[i];
                        a1yq[q] += tt * Yy[i];
                        a1zq[q] += tt * Yz[i];
                    } else if (p == 2) {
                        a1xq[q] += wv_ * m1x[i];
                        a1yq[q] += wv_ * m1y[i];
                        a1zq[q] += wv_ * m1z[i];
                    } else if (p == 3) {
                        a0q[q] += wv_ * (m1x[i] * Yx[i] + m1y[i] * Yy[i] + m1z[i] * Yz[i]);
                    } else {
                        a1xq[q] += wv_ * (m1y[i] * Yz[i] - m1z[i] * Yy[i]);
                        a1yq[q] += wv_ * (m1z[i] * Yx[i] - m1x[i] * Yz[i]);
                        a1zq[q] += wv_ * (m1x[i] * Yy[i] - m1y[i] * Yx[i]);
                    }
                }
            }
        }
    }

    // ---- reduce across the 4 g-groups and store ----
    #pragma unroll
    for (int q = 0; q < 4; ++q) {
        a0q[q]  += __shfl_xor(a0q[q], 16);  a0q[q]  += __shfl_xor(a0q[q], 32);
        a1xq[q] += __shfl_xor(a1xq[q], 16); a1xq[q] += __shfl_xor(a1xq[q], 32);
        a1yq[q] += __shfl_xor(a1yq[q], 16); a1yq[q] += __shfl_xor(a1yq[q], 32);
        a1zq[q] += __shfl_xor(a1zq[q], 16); a1zq[q] += __shfl_xor(a1zq[q], 32);
    }
    if (lane < 16) {
        float* ar = acc + (size_t)n * 256;
        #pragma unroll
        for (int q = 0; q < 4; ++q) {
            ar[16 * q + lane]       = a0q[q];
            ar[64 + 16 * q + lane]  = a1xq[q];
            ar[128 + 16 * q + lane] = a1yq[q];
            ar[192 + 16 * q + lane] = a1zq[q];
        }
    }
}

// ---------------------------------------------------------------------------
// Node epilogue
// ---------------------------------------------------------------------------
__global__ __launch_bounds__(256) void node_out_kernel(
    const float* __restrict__ acc, const float* __restrict__ node_feats,
    const int* __restrict__ node_specie,
    const float* __restrict__ Wd0, const float* __restrict__ Wd1,
    const float* __restrict__ Ws0, const float* __restrict__ Ws1,
    float* __restrict__ out)
{
    int n = blockIdx.x;
    int t = threadIdx.x;
    __shared__ float gates[64];
    int sp = node_specie[n];
    const float* accn = acc + (size_t)n * 256;
    const float* nf = node_feats + (size_t)n * 256;

    if (t < 128) {
        const float* ws0 = Ws0 + (size_t)sp * 64 * 128;
        float f = 0.f;
        #pragma unroll 8
        for (int c = 0; c < 64; ++c) {
            f += (0.25f * accn[c]) * Wd0[c * 128 + t];
            f += nf[c] * ws0[c * 128 + t];
        }
        float sv = f / (1.f + __expf(-f));
        if (t < 64) out[(size_t)n * 256 + t] = sv;
        else        gates[t - 64] = sv;
    }
    __syncthreads();
    if (t < 192) {
        int i = t >> 6;
        int c2 = t & 63;
        const float* ws1 = Ws1 + (size_t)sp * 64 * 64;
        float f = 0.f;
        #pragma unroll 8
        for (int cc = 0; cc < 64; ++cc) {
            f += (0.25f * accn[64 + i * 64 + cc]) * Wd1[cc * 64 + c2];
            f += nf[64 + cc * 3 + i] * ws1[cc * 64 + c2];
        }
        out[(size_t)n * 256 + 64 + c2 * 3 + i] = f * gates[c2];
    }
}

// ---------------------------------------------------------------------------
extern "C" void kernel_launch(void* const* d_in, const int* in_sizes, int n_in,
                              void* d_out, int out_size, void* d_ws, size_t ws_size,
                              hipStream_t stream) {
    const float* vectors     = (const float*)d_in[0];
    const float* node_feats  = (const float*)d_in[1];
    const int*   node_specie = (const int*)d_in[2];
    const int*   senders     = (const int*)d_in[3];
    const int*   receivers   = (const int*)d_in[4];
    const float* W0_up       = (const float*)d_in[5];
    const float* W1_up       = (const float*)d_in[6];
    const float* Wm1         = (const float*)d_in[7];
    const float* Wm2         = (const float*)d_in[8];
    const float* Wm3         = (const float*)d_in[9];
    const float* Ws0         = (const float*)d_in[10];
    const float* Ws1         = (const float*)d_in[11];
    const float* Wd0         = (const float*)d_in[12];
    const float* Wd1         = (const float*)d_in[13];
    float* out = (float*)d_out;

    int E = in_sizes[0] / 3;
    int N = in_sizes[1] / 256;

    float* u    = (float*)d_ws;                      // N*256 f32
    float* acc  = u + (size_t)N * 256;               // N*256 f32
    short* W1B  = (short*)(acc + (size_t)N * 256);   // 4*512 bf16
    short* Wm2B = W1B + 4 * 512;                     // 8*512 bf16
    short* W3B  = Wm2B + 8 * 512;                    // 40*512 bf16
    int*   cnt    = (int*)(W3B + 40 * 512);          // N
    int*   offs   = cnt + N;                         // N+1
    int*   cursor = offs + N + 1;                    // N
    int*   eidx   = cursor + N;                      // E

    hipMemsetAsync(cnt, 0, (size_t)N * sizeof(int), stream);

    prep_kernel<<<13, 256, 0, stream>>>(Wm1, Wm2, Wm3, W1B, Wm2B, W3B);
    hist_kernel<<<1024, 256, 0, stream>>>(receivers, cnt, E);
    scan_kernel<<<1, 1024, 0, stream>>>(cnt, offs, cursor, N);
    fill_kernel<<<1024, 256, 0, stream>>>(receivers, cursor, eidx, E);
    node_up_kernel<<<N, 256, 0, stream>>>(node_feats, W0_up, W1_up, u);
    edge_kernel<<<(N + 3) / 4, 256, 0, stream>>>(
        vectors, senders, eidx, offs, u, W1B, Wm2B, W3B, acc, N);
    node_out_kernel<<<N, 256, 0, stream>>>(
        acc, node_feats, node_specie, Wd0, Wd1, Ws0, Ws1, out);
}

// Round 6
// 677.280 us; speedup vs baseline: 1.2835x; 1.2835x over previous
//
#include <hip/hip_runtime.h>
#include <hip/hip_bf16.h>

typedef __attribute__((ext_vector_type(8))) short short8;
typedef __attribute__((ext_vector_type(4))) float f32x4;

__device__ __forceinline__ unsigned bf16u(float x) {
    unsigned u = __float_as_uint(x);
    return (u + 0x7fffu + ((u >> 16) & 1u)) >> 16;
}
__device__ __forceinline__ short bf16s(float x) { return (short)bf16u(x); }

// ---------------------------------------------------------------------------
// Prep: pack Wm1 (8x64), Wm2 (64x64), Wm3 (64x320) into MFMA B-fragment
// layout (bf16). Frag (t,kh): lane l holds B[k=kh*32+(l>>4)*8+i][col=16t+(l&15)].
// ---------------------------------------------------------------------------
__global__ __launch_bounds__(256) void prep_kernel(
    const float* __restrict__ Wm1, const float* __restrict__ Wm2,
    const float* __restrict__ Wm3,
    short* __restrict__ W1B, short* __restrict__ Wm2B, short* __restrict__ W3B)
{
    int idx = blockIdx.x * 256 + threadIdx.x;   // 52 frags * 64 lanes
    if (idx >= 52 * 64) return;
    int l = idx & 63, f = idx >> 6;
    int g = l >> 4, c = l & 15;
    short8 v;
    if (f < 4) {                 // W1B tile t=f: k=i (g==0 only), col=16f+c
        #pragma unroll
        for (int i = 0; i < 8; ++i)
            v[i] = (g == 0) ? bf16s(Wm1[(size_t)i * 64 + f * 16 + c]) : (short)0;
        *(short8*)(W1B + (size_t)f * 512 + l * 8) = v;
    } else if (f < 12) {         // Wm2B
        int f2 = f - 4, t = f2 >> 1, kh = f2 & 1;
        #pragma unroll
        for (int i = 0; i < 8; ++i)
            v[i] = bf16s(Wm2[(size_t)(kh * 32 + g * 8 + i) * 64 + t * 16 + c]);
        *(short8*)(Wm2B + (size_t)f2 * 512 + l * 8) = v;
    } else {                     // W3B
        int f3 = f - 12, t = f3 >> 1, kh = f3 & 1;
        #pragma unroll
        for (int i = 0; i < 8; ++i)
            v[i] = bf16s(Wm3[(size_t)(kh * 32 + g * 8 + i) * 320 + t * 16 + c]);
        *(short8*)(W3B + (size_t)f3 * 512 + l * 8) = v;
    }
}

// ---------------------------------------------------------------------------
// CSR build: histogram -> exclusive scan -> bucket fill (+ per-edge pack)
// ---------------------------------------------------------------------------
__global__ __launch_bounds__(256) void hist_kernel(
    const int* __restrict__ receivers, int* __restrict__ cnt, int E)
{
    int i = blockIdx.x * 256 + threadIdx.x;
    int stride = gridDim.x * 256;
    for (; i < E; i += stride) atomicAdd(&cnt[receivers[i]], 1);
}

__global__ __launch_bounds__(1024) void scan_kernel(
    const int* __restrict__ cnt, int* __restrict__ offs,
    int* __restrict__ cursor, int N)
{
    __shared__ int a[1024], b[1024];
    int t = threadIdx.x;
    int carry = 0;
    for (int base = 0; base < N; base += 1024) {
        int v = (base + t < N) ? cnt[base + t] : 0;
        a[t] = v;
        __syncthreads();
        int* src = a; int* dst = b;
        for (int off = 1; off < 1024; off <<= 1) {
            dst[t] = src[t] + ((t >= off) ? src[t - off] : 0);
            __syncthreads();
            int* tmp = src; src = dst; dst = tmp;
        }
        int incl = src[t];
        int tot  = src[1023];
        __syncthreads();
        if (base + t < N) {
            int e = carry + incl - v;
            offs[base + t] = e;
            cursor[base + t] = e;
        }
        carry += tot;
    }
    if (t == 0) offs[N] = carry;
}

// Scatter per-edge packed record into CSR position:
//  epackA[pos] = basis[0..7] as bf16 pairs (ready-to-use MFMA A-fragment data)
//  epackB[pos] = { Yx, Yy, Yz, sender_bits }
__global__ __launch_bounds__(256) void fill_pack_kernel(
    const float* __restrict__ vectors, const int* __restrict__ senders,
    const int* __restrict__ receivers, int* __restrict__ cursor,
    uint4* __restrict__ epackA, float4* __restrict__ epackB, int E)
{
    int i = blockIdx.x * 256 + threadIdx.x;
    int stride = gridDim.x * 256;
    for (; i < E; i += stride) {
        int pos = atomicAdd(&cursor[receivers[i]], 1);
        float vx = vectors[3 * (size_t)i + 0];
        float vy = vectors[3 * (size_t)i + 1];
        float vz = vectors[3 * (size_t)i + 2];
        float r = sqrtf(vx * vx + vy * vy + vz * vz);
        float ir = (r != 0.f) ? 1.f / r : 0.f;
        float ang = r * 0.6283185307179586f;   // pi/5
        float s1, c1;
        __sincosf(ang, &s1, &c1);
        float tc = 2.f * c1;
        float sb = s1, sp = 0.f;
        float coef = 0.6324555320336759f * ir;
        unsigned bw[4];
        #pragma unroll
        for (int h = 0; h < 4; ++h) {
            unsigned lo = bf16u(sb * coef);
            float nx = tc * sb - sp; sp = sb; sb = nx;
            unsigned hi = bf16u(sb * coef);
            nx = tc * sb - sp; sp = sb; sb = nx;
            bw[h] = lo | (hi << 16);
        }
        epackA[pos] = make_uint4(bw[0], bw[1], bw[2], bw[3]);
        epackB[pos] = make_float4(vx * ir, vy * ir, vz * ir,
                                  __int_as_float(senders[i]));
    }
}

// ---------------------------------------------------------------------------
// Node up-projection: u[n] = [u0(64) | u1x(64) | u1y(64) | u1z(64)]
// ---------------------------------------------------------------------------
__global__ __launch_bounds__(256) void node_up_kernel(
    const float* __restrict__ node_feats, const float* __restrict__ W0_up,
    const float* __restrict__ W1_up, float* __restrict__ u)
{
    int n = blockIdx.x;
    int t = threadIdx.x;
    const float* nf = node_feats + (size_t)n * 256;
    float f = 0.f;
    if (t < 64) {
        #pragma unroll 8
        for (int c = 0; c < 64; ++c) f += nf[c] * W0_up[c * 64 + t];
        u[(size_t)n * 256 + t] = f;
    } else {
        int i = (t - 64) >> 6;
        int d = t & 63;
        #pragma unroll 8
        for (int c = 0; c < 64; ++c) f += nf[64 + c * 3 + i] * W1_up[c * 64 + d];
        u[(size_t)n * 256 + 64 + i * 64 + d] = f;
    }
}

// ---------------------------------------------------------------------------
// Edge kernel v6: wave per receiver node, 16-edge MFMA chunks.
//  - prologue = ONE coalesced 32B load per edge (packed basis + meta)
//  - W3B fragments staged in LDS (40KB/block)
//  - u-gather ping-pong pipelined across q with sched_barrier fences
//    (prevents the R5 spill: only 2x16 m-values live)
// ---------------------------------------------------------------------------
__global__ __launch_bounds__(256, 3) void edge_kernel(
    const uint4* __restrict__ epackA, const float4* __restrict__ epackB,
    const int* __restrict__ offs, const float* __restrict__ u,
    const short* __restrict__ W1B, const short* __restrict__ Wm2B,
    const short* __restrict__ W3B, float* __restrict__ acc, int N)
{
    __shared__ __align__(16) short ldsW3[40 * 512];   // 40KB staged W3B
    __shared__ __align__(16) short ldsH[4][1024];     // per-wave h buffer (swz)
    __shared__ __align__(16) float ldsMeta[4][16][4]; // Y.xyz + sender

    {   // cooperative stage of W3B (2560 short8)
        const short8* src = (const short8*)W3B;
        short8* dst = (short8*)ldsW3;
        for (int i = threadIdx.x; i < 2560; i += 256) dst[i] = src[i];
    }
    __syncthreads();

    const int lane = threadIdx.x & 63;
    const int wv   = threadIdx.x >> 6;
    const int n    = blockIdx.x * 4 + wv;
    if (n >= N) return;
    const int c = lane & 15, g = lane >> 4;

    float a0q[4]  = {0.f, 0.f, 0.f, 0.f};
    float a1xq[4] = {0.f, 0.f, 0.f, 0.f};
    float a1yq[4] = {0.f, 0.f, 0.f, 0.f};
    float a1zq[4] = {0.f, 0.f, 0.f, 0.f};

    const int beg = offs[n], end = offs[n + 1];

    for (int p0 = beg; p0 < end; p0 += 16) {
        const int m = end - p0;

        // ---- prologue: lanes 0-15, one packed record each ----
        short8 basisA = {0, 0, 0, 0, 0, 0, 0, 0};
        if (lane < 16) {
            uint4 ba = epackA[p0 + lane];
            float4 mb = epackB[p0 + lane];
            if (lane >= m) {
                ba = make_uint4(0u, 0u, 0u, 0u);
                mb = make_float4(0.f, 0.f, 0.f, __int_as_float(0));
            }
            union { uint4 u4; short8 s8; } cv;
            cv.u4 = ba;
            basisA = cv.s8;
            *(float4*)&ldsMeta[wv][lane][0] = mb;
        }

        // ---- per-lane edge meta for its 4 rows, then early gather q0/q1 ----
        float Yx[4], Yy[4], Yz[4];
        int snd[4];
        #pragma unroll
        for (int i = 0; i < 4; ++i) {
            int row = 4 * g + i;
            float4 mt = *(const float4*)&ldsMeta[wv][row][0];
            Yx[i] = mt.x; Yy[i] = mt.y; Yz[i] = mt.z;
            snd[i] = __float_as_int(mt.w);
        }

#define PFETCH(Q, M0, M1X, M1Y, M1Z)                                        \
        _Pragma("unroll")                                                   \
        for (int i = 0; i < 4; ++i) {                                       \
            const float* us = u + (size_t)snd[i] * 256 + (16 * (Q) + c);    \
            M0[i]  = us[0];   M1X[i] = us[64];                              \
            M1Y[i] = us[128]; M1Z[i] = us[192];                             \
        }

#define COMPQ(Q, M0, M1X, M1Y, M1Z)                                         \
        _Pragma("unroll")                                                   \
        for (int p = 0; p < 5; ++p) {                                       \
            const int t = 4 * p + (Q);                                      \
            f32x4 w = {0.f, 0.f, 0.f, 0.f};                                 \
            short8 b0 = *(const short8*)(ldsW3 + (size_t)(t * 2) * 512 + lane * 8);     \
            short8 b1 = *(const short8*)(ldsW3 + (size_t)(t * 2 + 1) * 512 + lane * 8); \
            w = __builtin_amdgcn_mfma_f32_16x16x32_bf16(h2f0, b0, w, 0, 0, 0);          \
            w = __builtin_amdgcn_mfma_f32_16x16x32_bf16(h2f1, b1, w, 0, 0, 0);          \
            _Pragma("unroll")                                               \
            for (int i = 0; i < 4; ++i) {                                   \
                float wv_ = w[i];                                           \
                if (p == 0) {                                               \
                    a0q[Q] += wv_ * M0[i];                                  \
                } else if (p == 1) {                                        \
                    float tt = wv_ * M0[i];                                 \
                    a1xq[Q] += tt * Yx[i];                                  \
                    a1yq[Q] += tt * Yy[i];                                  \
                    a1zq[Q] += tt * Yz[i];                                  \
                } else if (p == 2) {                                        \
                    a1xq[Q] += wv_ * M1X[i];                                \
                    a1yq[Q] += wv_ * M1Y[i];                                \
                    a1zq[Q] += wv_ * M1Z[i];                                \
                } else if (p == 3) {                                        \
                    a0q[Q] += wv_ * (M1X[i] * Yx[i] + M1Y[i] * Yy[i] + M1Z[i] * Yz[i]); \
                } else {                                                    \
                    a1xq[Q] += wv_ * (M1Y[i] * Yz[i] - M1Z[i] * Yy[i]);     \
                    a1yq[Q] += wv_ * (M1Z[i] * Yx[i] - M1X[i] * Yz[i]);     \
                    a1zq[Q] += wv_ * (M1X[i] * Yy[i] - M1Y[i] * Yx[i]);     \
                }                                                           \
            }                                                               \
        }

        float m0A[4], m1xA[4], m1yA[4], m1zA[4];
        float m0B[4], m1xB[4], m1yB[4], m1zB[4];
        PFETCH(0, m0A, m1xA, m1yA, m1zA);
        PFETCH(1, m0B, m1xB, m1yB, m1zB);
        __builtin_amdgcn_sched_barrier(0);   // keep gathers issued here

        // ---- layer 1: 4 MFMAs; silu -> ldsH (swizzled bf16) ----
        #pragma unroll
        for (int t = 0; t < 4; ++t) {
            f32x4 h = {0.f, 0.f, 0.f, 0.f};
            short8 bf = *(const short8*)(W1B + (size_t)t * 512 + lane * 8);
            h = __builtin_amdgcn_mfma_f32_16x16x32_bf16(basisA, bf, h, 0, 0, 0);
            #pragma unroll
            for (int i = 0; i < 4; ++i) {
                float x = h[i];
                float h1 = x / (1.f + __expf(-x));
                int row = 4 * g + i;
                ldsH[wv][row * 64 + ((16 * t + c) ^ ((row & 7) << 3))] = bf16s(h1);
            }
        }
        short8 h1f0 = *(const short8*)&ldsH[wv][c * 64 + ((g * 8) ^ ((c & 7) << 3))];
        short8 h1f1 = *(const short8*)&ldsH[wv][c * 64 + ((32 + g * 8) ^ ((c & 7) << 3))];

        // ---- layer 2: 8 MFMAs; silu -> ldsH (reuse) ----
        #pragma unroll
        for (int t = 0; t < 4; ++t) {
            f32x4 h = {0.f, 0.f, 0.f, 0.f};
            short8 b0 = *(const short8*)(Wm2B + (size_t)(t * 2) * 512 + lane * 8);
            short8 b1 = *(const short8*)(Wm2B + (size_t)(t * 2 + 1) * 512 + lane * 8);
            h = __builtin_amdgcn_mfma_f32_16x16x32_bf16(h1f0, b0, h, 0, 0, 0);
            h = __builtin_amdgcn_mfma_f32_16x16x32_bf16(h1f1, b1, h, 0, 0, 0);
            #pragma unroll
            for (int i = 0; i < 4; ++i) {
                float x = h[i];
                float h2 = x / (1.f + __expf(-x));
                int row = 4 * g + i;
                ldsH[wv][row * 64 + ((16 * t + c) ^ ((row & 7) << 3))] = bf16s(h2);
            }
        }
        short8 h2f0 = *(const short8*)&ldsH[wv][c * 64 + ((g * 8) ^ ((c & 7) << 3))];
        short8 h2f1 = *(const short8*)&ldsH[wv][c * 64 + ((32 + g * 8) ^ ((c & 7) << 3))];

        // ---- layer 3 + fused messages, ping-pong pipelined over q ----
        COMPQ(0, m0A, m1xA, m1yA, m1zA);
        __builtin_amdgcn_sched_barrier(0);
        PFETCH(2, m0A, m1xA, m1yA, m1zA);
        COMPQ(1, m0B, m1xB, m1yB, m1zB);
        __builtin_amdgcn_sched_barrier(0);
        PFETCH(3, m0B, m1xB, m1yB, m1zB);
        COMPQ(2, m0A, m1xA, m1yA, m1zA);
        __builtin_amdgcn_sched_barrier(0);
        COMPQ(3, m0B, m1xB, m1yB, m1zB);
#undef PFETCH
#undef COMPQ
    }

    // ---- reduce across the 4 g-groups and store ----
    #pragma unroll
    for (int q = 0; q < 4; ++q) {
        a0q[q]  += __shfl_xor(a0q[q], 16);  a0q[q]  += __shfl_xor(a0q[q], 32);
        a1xq[q] += __shfl_xor(a1xq[q], 16); a1xq[q] += __shfl_xor(a1xq[q], 32);
        a1yq[q] += __shfl_xor(a1yq[q], 16); a1yq[q] += __shfl_xor(a1yq[q], 32);
        a1zq[q] += __shfl_xor(a1zq[q], 16); a1zq[q] += __shfl_xor(a1zq[q], 32);
    }
    if (lane < 16) {
        float* ar = acc + (size_t)n * 256;
        #pragma unroll
        for (int q = 0; q < 4; ++q) {
            ar[16 * q + lane]       = a0q[q];
            ar[64 + 16 * q + lane]  = a1xq[q];
            ar[128 + 16 * q + lane] = a1yq[q];
            ar[192 + 16 * q + lane] = a1zq[q];
        }
    }
}

// ---------------------------------------------------------------------------
// Node epilogue
// ---------------------------------------------------------------------------
__global__ __launch_bounds__(256) void node_out_kernel(
    const float* __restrict__ acc, const float* __restrict__ node_feats,
    const int* __restrict__ node_specie,
    const float* __restrict__ Wd0, const float* __restrict__ Wd1,
    const float* __restrict__ Ws0, const float* __restrict__ Ws1,
    float* __restrict__ out)
{
    int n = blockIdx.x;
    int t = threadIdx.x;
    __shared__ float gates[64];
    int sp = node_specie[n];
    const float* accn = acc + (size_t)n * 256;
    const float* nf = node_feats + (size_t)n * 256;

    if (t < 128) {
        const float* ws0 = Ws0 + (size_t)sp * 64 * 128;
        float f = 0.f;
        #pragma unroll 8
        for (int c = 0; c < 64; ++c) {
            f += (0.25f * accn[c]) * Wd0[c * 128 + t];
            f += nf[c] * ws0[c * 128 + t];
        }
        float sv = f / (1.f + __expf(-f));
        if (t < 64) out[(size_t)n * 256 + t] = sv;
        else        gates[t - 64] = sv;
    }
    __syncthreads();
    if (t < 192) {
        int i = t >> 6;
        int c2 = t & 63;
        const float* ws1 = Ws1 + (size_t)sp * 64 * 64;
        float f = 0.f;
        #pragma unroll 8
        for (int cc = 0; cc < 64; ++cc) {
            f += (0.25f * accn[64 + i * 64 + cc]) * Wd1[cc * 64 + c2];
            f += nf[64 + cc * 3 + i] * ws1[cc * 64 + c2];
        }
        out[(size_t)n * 256 + 64 + c2 * 3 + i] = f * gates[c2];
    }
}

// ---------------------------------------------------------------------------
extern "C" void kernel_launch(void* const* d_in, const int* in_sizes, int n_in,
                              void* d_out, int out_size, void* d_ws, size_t ws_size,
                              hipStream_t stream) {
    const float* vectors     = (const float*)d_in[0];
    const float* node_feats  = (const float*)d_in[1];
    const int*   node_specie = (const int*)d_in[2];
    const int*   senders     = (const int*)d_in[3];
    const int*   receivers   = (const int*)d_in[4];
    const float* W0_up       = (const float*)d_in[5];
    const float* W1_up       = (const float*)d_in[6];
    const float* Wm1         = (const float*)d_in[7];
    const float* Wm2         = (const float*)d_in[8];
    const float* Wm3         = (const float*)d_in[9];
    const float* Ws0         = (const float*)d_in[10];
    const float* Ws1         = (const float*)d_in[11];
    const float* Wd0         = (const float*)d_in[12];
    const float* Wd1         = (const float*)d_in[13];
    float* out = (float*)d_out;

    int E = in_sizes[0] / 3;
    int N = in_sizes[1] / 256;

    char* wp = (char*)d_ws;
    float* u      = (float*)wp;                 wp += (size_t)N * 256 * 4;
    float* acc    = (float*)wp;                 wp += (size_t)N * 256 * 4;
    uint4* epackA = (uint4*)wp;                 wp += (size_t)(E + 16) * 16;
    float4* epackB = (float4*)wp;               wp += (size_t)(E + 16) * 16;
    short* W1B    = (short*)wp;                 wp += 4 * 512 * 2;
    short* Wm2B   = (short*)wp;                 wp += 8 * 512 * 2;
    short* W3B    = (short*)wp;                 wp += 40 * 512 * 2;
    int*   cnt    = (int*)wp;                   wp += (size_t)N * 4;
    int*   offs   = (int*)wp;                   wp += (size_t)(N + 1) * 4;
    int*   cursor = (int*)wp;                   wp += (size_t)N * 4;

    hipMemsetAsync(cnt, 0, (size_t)N * sizeof(int), stream);

    prep_kernel<<<13, 256, 0, stream>>>(Wm1, Wm2, Wm3, W1B, Wm2B, W3B);
    hist_kernel<<<1024, 256, 0, stream>>>(receivers, cnt, E);
    scan_kernel<<<1, 1024, 0, stream>>>(cnt, offs, cursor, N);
    fill_pack_kernel<<<1024, 256, 0, stream>>>(
        vectors, senders, receivers, cursor, epackA, epackB, E);
    node_up_kernel<<<N, 256, 0, stream>>>(node_feats, W0_up, W1_up, u);
    edge_kernel<<<(N + 3) / 4, 256, 0, stream>>>(
        epackA, epackB, offs, u, W1B, Wm2B, W3B, acc, N);
    node_out_kernel<<<N, 256, 0, stream>>>(
        acc, node_feats, node_specie, Wd0, Wd1, Ws0, Ws1, out);
}